// Round 4
// baseline (83.665 us; speedup 1.0000x reference)
//
#include <hip/hip_runtime.h>
#include <hip/hip_bf16.h>

// AdaptiveTripletLoss on MI355X (gfx950).
// feats [4096,512] f32, labels [4096] i32 -> scalar f32 loss.
// R3: symmetric 528-tile Gram + BK=32 double-buffer (34KB LDS) so all 528
// blocks are co-resident in ONE balanced round (R2's 66KB LDS -> 2 blocks/CU
// -> 512+16 split with a ~20us straggler tail). Counted-vmcnt 2-barrier loop.

#define NN 4096
#define DD 512
#define NCLS 64

typedef __bf16 bf16x8 __attribute__((ext_vector_type(8)));
typedef float f32x4 __attribute__((ext_vector_type(4)));

__device__ __forceinline__ void gload_lds16(const void* g, void* l) {
  __builtin_amdgcn_global_load_lds(
      (const __attribute__((address_space(1))) void*)g,
      (__attribute__((address_space(3))) void*)l, 16, 0, 0);
}

// ---------------- kernel 1: per-class stats ----------------
__global__ __launch_bounds__(512) void k_stats(
    const float* __restrict__ feats, const int* __restrict__ labels,
    float* __restrict__ counts, float* __restrict__ cmean,
    float* __restrict__ uncert) {
  __shared__ __align__(16) int slab[NN];
  __shared__ int list[NN];
  __shared__ int chunk_off[64];
  __shared__ int sM;
  __shared__ float sred[512];
  const int c = blockIdx.x;
  const int t = threadIdx.x;
  const int lane = t & 63;
  const int wv = t >> 6;
  for (int i = t; i < NN; i += 512) slab[i] = labels[i];
  __syncthreads();
  for (int ch = wv; ch < 64; ch += 8) {
    const unsigned long long m = __ballot(slab[ch * 64 + lane] == c);
    if (lane == 0) chunk_off[ch] = __popcll(m);
  }
  __syncthreads();
  if (wv == 0) {
    const int v = chunk_off[lane];
    int inc = v;
#pragma unroll
    for (int off = 1; off < 64; off <<= 1) {
      const int o = __shfl_up(inc, off);
      if (lane >= off) inc += o;
    }
    chunk_off[lane] = inc - v;
    if (lane == 63) sM = inc;
  }
  __syncthreads();
  const int M = sM;
  for (int ch = wv; ch < 64; ch += 8) {
    const bool my = (slab[ch * 64 + lane] == c);
    const unsigned long long m = __ballot(my);
    if (my) {
      const int pos = chunk_off[ch] + __popcll(m & ((1ULL << lane) - 1ULL));
      list[pos] = ch * 64 + lane;
    }
  }
  __syncthreads();
  float s1 = 0.f, s2 = 0.f;
  int m = 0;
  for (; m + 8 <= M; m += 8) {
    float v[8];
#pragma unroll
    for (int e = 0; e < 8; ++e) v[e] = feats[(size_t)list[m + e] * DD + t];
#pragma unroll
    for (int e = 0; e < 8; ++e) { s1 += v[e]; s2 += v[e] * v[e]; }
  }
  for (; m < M; ++m) {
    const float v = feats[(size_t)list[m] * DD + t];
    s1 += v; s2 += v * v;
  }
  const float den = fmaxf((float)M, 1.f);
  const float mean = s1 / den;
  const float var = fmaxf(s2 / den - mean * mean, 0.f);
  cmean[c * DD + t] = mean;
  sred[t] = var;
  __syncthreads();
  for (int s = 256; s > 0; s >>= 1) {
    if (t < s) sred[t] += sred[t + s];
    __syncthreads();
  }
  if (t == 0) {
    uncert[c] = sred[0] / (float)DD;
    counts[c] = (float)M;
  }
}

// ---------------- kernel 2: per-row transform ----------------
__global__ __launch_bounds__(256) void k_row(
    const float* __restrict__ feats, const int* __restrict__ labels,
    const float* __restrict__ cmean, unsigned short* __restrict__ fb,
    float* __restrict__ sqb, float* __restrict__ cd2) {
  const int w = threadIdx.x >> 6;
  const int lane = threadIdx.x & 63;
  const int row = blockIdx.x * 4 + w;
  const int lab = labels[row];
  const float4* fr = (const float4*)(feats + (size_t)row * DD);
  const float4* cm = (const float4*)(cmean + (size_t)lab * DD);
  float sq = 0.f, c2 = 0.f;
  unsigned int ob[4];
#pragma unroll
  for (int h = 0; h < 2; ++h) {
    const float4 f = fr[lane * 2 + h];
    const float4 cv = cm[lane * 2 + h];
    const float fe[4] = {f.x, f.y, f.z, f.w};
    const float ce[4] = {cv.x, cv.y, cv.z, cv.w};
    unsigned short us[4];
#pragma unroll
    for (int e = 0; e < 4; ++e) {
      const __bf16 b = (__bf16)fe[e];
      const float bf = (float)b;
      sq += bf * bf;
      const float dd = fe[e] - ce[e];
      c2 += dd * dd;
      us[e] = __builtin_bit_cast(unsigned short, b);
    }
    ob[h * 2]     = (unsigned int)us[0] | ((unsigned int)us[1] << 16);
    ob[h * 2 + 1] = (unsigned int)us[2] | ((unsigned int)us[3] << 16);
  }
  *(uint4*)(fb + (size_t)row * DD + lane * 8) = make_uint4(ob[0], ob[1], ob[2], ob[3]);
#pragma unroll
  for (int off = 32; off > 0; off >>= 1) {
    sq += __shfl_xor(sq, off);
    c2 += __shfl_xor(c2, off);
  }
  if (lane == 0) {
    sqb[row] = sq;
    cd2[row] = c2;
  }
}

// ---------------- kernel 3: symmetric fused Gram + dual-direction reductions --
// 528 upper-triangle 128x128 tiles, BK=32 double-buffered (34KB LDS -> all
// blocks co-resident, no straggler tail). Swizzle: store chunk c^((row>>1)&3),
// read chunk g4^((rin>>1)&3) -> lane gets global k-chunk g4; 2-way banks (free).
__global__ __launch_bounds__(256) void k_gemm(
    const unsigned short* __restrict__ fb, const float* __restrict__ sqb,
    const int* __restrict__ labels,
    float* __restrict__ php, float* __restrict__ phn,
    float* __restrict__ pst, float* __restrict__ pss) {
  __shared__ __align__(16) unsigned short sA[2][128 * 32];
  __shared__ __align__(16) unsigned short sB[2][128 * 32];
  __shared__ int s_labi[128], s_labj[128];
  __shared__ float s_sqi[128], s_sqj[128];

  const int bid = blockIdx.x;
  const int swz = (bid & 7) * 66 + (bid >> 3);  // bijective: 528 = 8*66
  int kk = swz, ib = 0;
  while (kk >= 32 - ib) { kk -= 32 - ib; ++ib; }  // triangular decode
  const int jb = ib + kk;
  const int ibase = ib << 7, jbase = jb << 7;
  const int t = threadIdx.x;
  const int lane = t & 63;
  const int w = t >> 6;
  const int wm = w >> 1, wn = w & 1;

  if (t < 128) {
    s_labi[t] = labels[ibase + t];
    s_labj[t] = labels[jbase + t];
    s_sqi[t] = sqb[ibase + t];
    s_sqj[t] = sqb[jbase + t];
  }

  f32x4 acc[4][4];
#pragma unroll
  for (int mi = 0; mi < 4; ++mi)
#pragma unroll
    for (int nj = 0; nj < 4; ++nj)
      acc[mi][nj] = (f32x4){0.f, 0.f, 0.f, 0.f};

  // stage one BK=32 K-slab (128 rows x 32 elems = 512 x 16B chunks per matrix)
  auto stage = [&](int nb, int kt) {
#pragma unroll
    for (int r = 0; r < 2; ++r) {
      const int q = (r << 8) + t;       // 0..511 chunk id
      const int row = q >> 2;           // 0..127
      const int ch = q & 3;             // 4 chunks of 16B per 32-elem row
      const int csrc = ch ^ ((row >> 1) & 3);
      const int ksrc = (kt << 5) + (csrc << 3);
      gload_lds16(fb + (size_t)(ibase + row) * DD + ksrc, &sA[nb][q << 3]);
      gload_lds16(fb + (size_t)(jbase + row) * DD + ksrc, &sB[nb][q << 3]);
    }
  };

  stage(0, 0);

  const int rin = lane & 15;
  const int g4 = lane >> 4;
  const int koff = ((g4 ^ ((rin >> 1) & 3)) << 4);  // swizzled 16B chunk in 64B row
  const int abase = ((wm << 6) + rin) << 6;         // row*64 bytes
  const int bbase = ((wn << 6) + rin) << 6;

#pragma unroll 2
  for (int kt = 0; kt < 16; ++kt) {
    const int cur = kt & 1;
    if (kt < 15) {
      stage(cur ^ 1, kt + 1);
      asm volatile("s_waitcnt vmcnt(4)" ::: "memory");  // prev slab landed
    } else {
      asm volatile("s_waitcnt vmcnt(0)" ::: "memory");
    }
    __builtin_amdgcn_s_barrier();
    const char* A = (const char*)sA[cur];
    const char* B = (const char*)sB[cur];
    bf16x8 af[4], bg[4];
#pragma unroll
    for (int mi = 0; mi < 4; ++mi)
      af[mi] = *(const bf16x8*)(A + abase + (mi << 10) + koff);
#pragma unroll
    for (int nj = 0; nj < 4; ++nj)
      bg[nj] = *(const bf16x8*)(B + bbase + (nj << 10) + koff);
#pragma unroll
    for (int mi = 0; mi < 4; ++mi)
#pragma unroll
      for (int nj = 0; nj < 4; ++nj)
        acc[mi][nj] = __builtin_amdgcn_mfma_f32_16x16x32_bf16(
            af[mi], bg[nj], acc[mi][nj], 0, 0, 0);
    asm volatile("s_waitcnt lgkmcnt(0)" ::: "memory");  // ds_reads done
    __builtin_amdgcn_s_barrier();                       // safe to overwrite cur
  }

  // epilogue. C/D layout: i = wm*64+mi*16+g4*4+r, j = wn*64+nj*16+rin.
  float qj[4];
  int lj[4];
#pragma unroll
  for (int nj = 0; nj < 4; ++nj) {
    const int cl = (wn << 6) + (nj << 4) + rin;
    qj[nj] = s_sqj[cl];
    lj[nj] = s_labj[cl];
  }
  float hp2[4], hn2[4], st2[4], ss2[4];
#pragma unroll
  for (int nj = 0; nj < 4; ++nj) { hp2[nj] = 0.f; hn2[nj] = 1e30f; st2[nj] = 0.f; ss2[nj] = 0.f; }

  const int jidx = (jb << 1) + wn;
#pragma unroll
  for (int mi = 0; mi < 4; ++mi) {
#pragma unroll
    for (int r = 0; r < 4; ++r) {
      const int rl = (wm << 6) + (mi << 4) + (g4 << 2) + r;
      const float qi = s_sqi[rl];
      const int li = s_labi[rl];
      float hp = 0.f, hn = 1e30f, st = 0.f, ss = 0.f;
#pragma unroll
      for (int nj = 0; nj < 4; ++nj) {
        const float g = acc[mi][nj][r];
        float d2 = qi + qj[nj] - 2.f * g;
        d2 = fmaxf(d2, 0.f);
        const float dist = sqrtf(d2);
        const bool same = (li == lj[nj]);
        const float dp = same ? dist : 0.f;
        const float dn = same ? 1e30f : dist;
        hp = fmaxf(hp, dp);
        hn = fminf(hn, dn);
        st += dist;
        ss += dp;
        hp2[nj] = fmaxf(hp2[nj], dp);   // dir-2 accumulation (reduce over i)
        hn2[nj] = fminf(hn2[nj], dn);
        st2[nj] += dist;
        ss2[nj] += dp;
      }
#pragma unroll
      for (int off = 1; off < 16; off <<= 1) {
        hp = fmaxf(hp, __shfl_xor(hp, off));
        hn = fminf(hn, __shfl_xor(hn, off));
        st += __shfl_xor(st, off);
        ss += __shfl_xor(ss, off);
      }
      if (rin == 0) {
        const int grow = ibase + rl;
        php[jidx * NN + grow] = hp;
        phn[jidx * NN + grow] = hn;
        pst[jidx * NN + grow] = st;
        pss[jidx * NN + grow] = ss;
      }
    }
  }

  if (ib != jb) {  // dir-2: mirror rows (jbase+*), columns = ibase-block
    const int iidx = (ib << 1) + wm;
#pragma unroll
    for (int nj = 0; nj < 4; ++nj) {
      float hp = hp2[nj], hn = hn2[nj], st = st2[nj], ss = ss2[nj];
#pragma unroll
      for (int off = 16; off < 64; off <<= 1) {
        hp = fmaxf(hp, __shfl_xor(hp, off));
        hn = fminf(hn, __shfl_xor(hn, off));
        st += __shfl_xor(st, off);
        ss += __shfl_xor(ss, off);
      }
      if (g4 == 0) {
        const int grow = jbase + (wn << 6) + (nj << 4) + rin;
        php[iidx * NN + grow] = hp;
        phn[iidx * NN + grow] = hn;
        pst[iidx * NN + grow] = st;
        pss[iidx * NN + grow] = ss;
      }
    }
  }
}

// ---------------- kernel 4: combine partials, per-row margin ----------------
__global__ __launch_bounds__(128) void k_fin1(
    const int* __restrict__ labels, const float* __restrict__ counts,
    const float* __restrict__ uncert, const float* __restrict__ cd2,
    const float* __restrict__ php, const float* __restrict__ phn,
    const float* __restrict__ pst, const float* __restrict__ pss,
    float* __restrict__ pf) {
  const int t = threadIdx.x;
  const int row = blockIdx.x * 128 + t;
  float hp = 0.f, hn = 1e30f, st = 0.f, ss = 0.f;
#pragma unroll 8
  for (int j = 0; j < 64; ++j) {
    hp = fmaxf(hp, php[j * NN + row]);
    hn = fminf(hn, phn[j * NN + row]);
    st += pst[j * NN + row];
    ss += pss[j * NN + row];
  }
  const int lab = labels[row];
  const float cnt = counts[lab];
  const float pos = cnt - 1.f;
  const float neg = (float)NN - cnt;
  const float mean_pos = ss / fmaxf(pos, 1.f);
  const float mean_neg = (st - ss) / fmaxf(neg, 1.f);
  const float c2 = cd2[row];
  const float cdist = (c2 > 0.f) ? sqrtf(c2) : 0.f;
  const float margin = 0.1f + 0.1f * (mean_neg - mean_pos) + 0.1f * (cdist * uncert[lab]);
  const float ps = fmaxf(hp - hn + margin, 0.f);
  const bool valid = (pos > 0.f) && (neg > 0.f);
  __shared__ float r1[128], r2[128];
  r1[t] = valid ? ps : 0.f;
  r2[t] = valid ? 1.f : 0.f;
  __syncthreads();
  for (int s = 64; s > 0; s >>= 1) {
    if (t < s) { r1[t] += r1[t + s]; r2[t] += r2[t + s]; }
    __syncthreads();
  }
  if (t == 0) {
    pf[2 * blockIdx.x] = r1[0];
    pf[2 * blockIdx.x + 1] = r2[0];
  }
}

// ---------------- kernel 5: final scalar ----------------
__global__ __launch_bounds__(64) void k_fin2(const float* __restrict__ pf,
                                             float* __restrict__ out) {
  const int t = threadIdx.x;
  float s = 0.f, c = 0.f;
  if (t < 32) { s = pf[2 * t]; c = pf[2 * t + 1]; }
#pragma unroll
  for (int off = 32; off > 0; off >>= 1) {
    s += __shfl_xor(s, off);
    c += __shfl_xor(c, off);
  }
  if (t == 0) out[0] = (c > 0.f) ? (s / fmaxf(c, 1.f)) : 0.f;
}

extern "C" void kernel_launch(void* const* d_in, const int* in_sizes, int n_in,
                              void* d_out, int out_size, void* d_ws, size_t ws_size,
                              hipStream_t stream) {
  (void)in_sizes; (void)n_in; (void)out_size; (void)ws_size;
  const float* feats = (const float*)d_in[0];
  const int* labels = (const int*)d_in[1];
  char* w = (char*)d_ws;
  float* counts = (float*)(w + 0);
  float* uncert = (float*)(w + 1024);
  float* sqb    = (float*)(w + 2048);
  float* cd2    = (float*)(w + 18432);
  float* pf     = (float*)(w + 34816);
  float* cmean  = (float*)(w + 36864);
  unsigned short* fb = (unsigned short*)(w + 167936);
  float* php = (float*)(w + 4362240);
  float* phn = (float*)(w + 5410816);
  float* pst = (float*)(w + 6459392);
  float* pss = (float*)(w + 7507968);

  k_stats<<<dim3(64), dim3(512), 0, stream>>>(feats, labels, counts, cmean, uncert);
  k_row<<<dim3(1024), dim3(256), 0, stream>>>(feats, labels, cmean, fb, sqb, cd2);
  k_gemm<<<dim3(528), dim3(256), 0, stream>>>(fb, sqb, labels, php, phn, pst, pss);
  k_fin1<<<dim3(32), dim3(128), 0, stream>>>(labels, counts, uncert, cd2,
                                             php, phn, pst, pss, pf);
  k_fin2<<<dim3(1), dim3(64), 0, stream>>>(pf, (float*)d_out);
}

// Round 5
// 75.813 us; speedup vs baseline: 1.1036x; 1.1036x over previous
//
#include <hip/hip_runtime.h>
#include <hip/hip_bf16.h>

// AdaptiveTripletLoss on MI355X (gfx950).
// feats [4096,512] f32, labels [4096] i32 -> scalar f32 loss.
// R4: symmetric Gram with R2's PROVEN BK=64 K-loop (24 tiles/us) on a
// BALANCED 512-block dual-tile schedule (blocks 0..15 take the 16 extra
// tiles). Partials repacked [row][64]; k_fin1 parallelized (256 blocks).

#define NN 4096
#define DD 512
#define NCLS 64

typedef __bf16 bf16x8 __attribute__((ext_vector_type(8)));
typedef float f32x4 __attribute__((ext_vector_type(4)));

__device__ __forceinline__ void gload_lds16(const void* g, void* l) {
  __builtin_amdgcn_global_load_lds(
      (const __attribute__((address_space(1))) void*)g,
      (__attribute__((address_space(3))) void*)l, 16, 0, 0);
}

// ---------------- kernel 1: per-class stats ----------------
__global__ __launch_bounds__(512) void k_stats(
    const float* __restrict__ feats, const int* __restrict__ labels,
    float* __restrict__ counts, float* __restrict__ cmean,
    float* __restrict__ uncert) {
  __shared__ __align__(16) int slab[NN];
  __shared__ int list[NN];
  __shared__ int chunk_off[64];
  __shared__ int sM;
  __shared__ float sred[512];
  const int c = blockIdx.x;
  const int t = threadIdx.x;
  const int lane = t & 63;
  const int wv = t >> 6;
  for (int i = t; i < NN; i += 512) slab[i] = labels[i];
  __syncthreads();
  for (int ch = wv; ch < 64; ch += 8) {
    const unsigned long long m = __ballot(slab[ch * 64 + lane] == c);
    if (lane == 0) chunk_off[ch] = __popcll(m);
  }
  __syncthreads();
  if (wv == 0) {
    const int v = chunk_off[lane];
    int inc = v;
#pragma unroll
    for (int off = 1; off < 64; off <<= 1) {
      const int o = __shfl_up(inc, off);
      if (lane >= off) inc += o;
    }
    chunk_off[lane] = inc - v;
    if (lane == 63) sM = inc;
  }
  __syncthreads();
  const int M = sM;
  for (int ch = wv; ch < 64; ch += 8) {
    const bool my = (slab[ch * 64 + lane] == c);
    const unsigned long long m = __ballot(my);
    if (my) {
      const int pos = chunk_off[ch] + __popcll(m & ((1ULL << lane) - 1ULL));
      list[pos] = ch * 64 + lane;
    }
  }
  __syncthreads();
  float s1 = 0.f, s2 = 0.f;
  int m = 0;
  for (; m + 8 <= M; m += 8) {
    float v[8];
#pragma unroll
    for (int e = 0; e < 8; ++e) v[e] = feats[(size_t)list[m + e] * DD + t];
#pragma unroll
    for (int e = 0; e < 8; ++e) { s1 += v[e]; s2 += v[e] * v[e]; }
  }
  for (; m < M; ++m) {
    const float v = feats[(size_t)list[m] * DD + t];
    s1 += v; s2 += v * v;
  }
  const float den = fmaxf((float)M, 1.f);
  const float mean = s1 / den;
  const float var = fmaxf(s2 / den - mean * mean, 0.f);
  cmean[c * DD + t] = mean;
  sred[t] = var;
  __syncthreads();
  for (int s = 256; s > 0; s >>= 1) {
    if (t < s) sred[t] += sred[t + s];
    __syncthreads();
  }
  if (t == 0) {
    uncert[c] = sred[0] / (float)DD;
    counts[c] = (float)M;
  }
}

// ---------------- kernel 2: per-row transform ----------------
__global__ __launch_bounds__(256) void k_row(
    const float* __restrict__ feats, const int* __restrict__ labels,
    const float* __restrict__ cmean, unsigned short* __restrict__ fb,
    float* __restrict__ sqb, float* __restrict__ cd2) {
  const int w = threadIdx.x >> 6;
  const int lane = threadIdx.x & 63;
  const int row = blockIdx.x * 4 + w;
  const int lab = labels[row];
  const float4* fr = (const float4*)(feats + (size_t)row * DD);
  const float4* cm = (const float4*)(cmean + (size_t)lab * DD);
  float sq = 0.f, c2 = 0.f;
  unsigned int ob[4];
#pragma unroll
  for (int h = 0; h < 2; ++h) {
    const float4 f = fr[lane * 2 + h];
    const float4 cv = cm[lane * 2 + h];
    const float fe[4] = {f.x, f.y, f.z, f.w};
    const float ce[4] = {cv.x, cv.y, cv.z, cv.w};
    unsigned short us[4];
#pragma unroll
    for (int e = 0; e < 4; ++e) {
      const __bf16 b = (__bf16)fe[e];
      const float bf = (float)b;
      sq += bf * bf;
      const float dd = fe[e] - ce[e];
      c2 += dd * dd;
      us[e] = __builtin_bit_cast(unsigned short, b);
    }
    ob[h * 2]     = (unsigned int)us[0] | ((unsigned int)us[1] << 16);
    ob[h * 2 + 1] = (unsigned int)us[2] | ((unsigned int)us[3] << 16);
  }
  *(uint4*)(fb + (size_t)row * DD + lane * 8) = make_uint4(ob[0], ob[1], ob[2], ob[3]);
#pragma unroll
  for (int off = 32; off > 0; off >>= 1) {
    sq += __shfl_xor(sq, off);
    c2 += __shfl_xor(c2, off);
  }
  if (lane == 0) {
    sqb[row] = sq;
    cd2[row] = c2;
  }
}

// ---------------- kernel 3: symmetric fused Gram, dual-tile balanced ----------
// 528 upper-triangle 128x128 tiles on 512 blocks (2/CU, one round); blocks
// 0..15 process a second tile. K-loop = R2's proven BK=64 double-buffer with
// plain __syncthreads. Dual-direction epilogue writes partials [row][64].
__global__ __launch_bounds__(256) void k_gemm(
    const unsigned short* __restrict__ fb, const float* __restrict__ sqb,
    const int* __restrict__ labels,
    float* __restrict__ php, float* __restrict__ phn,
    float* __restrict__ pst, float* __restrict__ pss) {
  __shared__ __align__(16) unsigned short sA[2][128 * 64];
  __shared__ __align__(16) unsigned short sB[2][128 * 64];
  __shared__ int s_labi[128], s_labj[128];
  __shared__ float s_sqi[128], s_sqj[128];

  const int bid = blockIdx.x;
  const int t = threadIdx.x;
  const int lane = t & 63;
  const int w = t >> 6;
  const int wm = w >> 1, wn = w & 1;
  const int rin = lane & 15;
  const int g4 = lane >> 4;
  const int swzbyte = (g4 ^ (rin & 7)) << 4;
  const int abase = ((wm << 6) + rin) << 7;
  const int bbase = ((wn << 6) + rin) << 7;

  const int b0 = (bid & 7) * 64 + (bid >> 3);  // bijective over 512
  const int ntile = (bid < 16) ? 2 : 1;

  for (int tt = 0; tt < ntile; ++tt) {
    const int L = (tt == 0) ? b0 : (512 + bid);
    int kk = L, ib = 0;
    while (kk >= 32 - ib) { kk -= 32 - ib; ++ib; }  // triangular decode
    const int jb = ib + kk;
    const int ibase = ib << 7, jbase = jb << 7;

    __syncthreads();  // protect s_lab/s_sq + LDS from previous tile's readers
    if (t < 128) {
      s_labi[t] = labels[ibase + t];
      s_labj[t] = labels[jbase + t];
      s_sqi[t] = sqb[ibase + t];
      s_sqj[t] = sqb[jbase + t];
    }

    auto stage = [&](int nb, int kt) {
#pragma unroll
      for (int r = 0; r < 4; ++r) {
        const int q = (r << 8) + t;
        const int row = q >> 3;
        const int ch = q & 7;
        const int ksrc = (kt << 6) + ((ch ^ (row & 7)) << 3);
        gload_lds16(fb + (size_t)(ibase + row) * DD + ksrc, &sA[nb][q << 3]);
        gload_lds16(fb + (size_t)(jbase + row) * DD + ksrc, &sB[nb][q << 3]);
      }
    };

    f32x4 acc[4][4];
#pragma unroll
    for (int mi = 0; mi < 4; ++mi)
#pragma unroll
      for (int nj = 0; nj < 4; ++nj)
        acc[mi][nj] = (f32x4){0.f, 0.f, 0.f, 0.f};

    stage(0, 0);
    __syncthreads();

    int cur = 0;
    for (int kt = 0; kt < 8; ++kt) {
      if (kt < 7) stage(cur ^ 1, kt + 1);
      const char* A = (const char*)sA[cur];
      const char* B = (const char*)sB[cur];
#pragma unroll
      for (int ks = 0; ks < 2; ++ks) {
        bf16x8 af[4], bg[4];
#pragma unroll
        for (int mi = 0; mi < 4; ++mi)
          af[mi] = *(const bf16x8*)(A + abase + (mi << 11) + (swzbyte ^ (ks << 6)));
#pragma unroll
        for (int nj = 0; nj < 4; ++nj)
          bg[nj] = *(const bf16x8*)(B + bbase + (nj << 11) + (swzbyte ^ (ks << 6)));
#pragma unroll
        for (int mi = 0; mi < 4; ++mi)
#pragma unroll
          for (int nj = 0; nj < 4; ++nj)
            acc[mi][nj] = __builtin_amdgcn_mfma_f32_16x16x32_bf16(
                af[mi], bg[nj], acc[mi][nj], 0, 0, 0);
      }
      __syncthreads();  // drains vmcnt+lgkm: next buffer ready, cur reusable
      cur ^= 1;
    }

    // epilogue. C/D layout: i = wm*64+mi*16+g4*4+r, j = wn*64+nj*16+rin.
    float qj[4];
    int lj[4];
#pragma unroll
    for (int nj = 0; nj < 4; ++nj) {
      const int cl = (wn << 6) + (nj << 4) + rin;
      qj[nj] = s_sqj[cl];
      lj[nj] = s_labj[cl];
    }
    float hp2[4], hn2[4], st2[4], ss2[4];
#pragma unroll
    for (int nj = 0; nj < 4; ++nj) { hp2[nj] = 0.f; hn2[nj] = 1e30f; st2[nj] = 0.f; ss2[nj] = 0.f; }

    const int jidx = (jb << 1) + wn;
#pragma unroll
    for (int mi = 0; mi < 4; ++mi) {
#pragma unroll
      for (int r = 0; r < 4; ++r) {
        const int rl = (wm << 6) + (mi << 4) + (g4 << 2) + r;
        const float qi = s_sqi[rl];
        const int li = s_labi[rl];
        float hp = 0.f, hn = 1e30f, st = 0.f, ss = 0.f;
#pragma unroll
        for (int nj = 0; nj < 4; ++nj) {
          const float g = acc[mi][nj][r];
          float d2 = qi + qj[nj] - 2.f * g;
          d2 = fmaxf(d2, 0.f);
          const float dist = sqrtf(d2);
          const bool same = (li == lj[nj]);
          const float dp = same ? dist : 0.f;
          const float dn = same ? 1e30f : dist;
          hp = fmaxf(hp, dp);
          hn = fminf(hn, dn);
          st += dist;
          ss += dp;
          hp2[nj] = fmaxf(hp2[nj], dp);   // dir-2 (reduce over i)
          hn2[nj] = fminf(hn2[nj], dn);
          st2[nj] += dist;
          ss2[nj] += dp;
        }
#pragma unroll
        for (int off = 1; off < 16; off <<= 1) {
          hp = fmaxf(hp, __shfl_xor(hp, off));
          hn = fminf(hn, __shfl_xor(hn, off));
          st += __shfl_xor(st, off);
          ss += __shfl_xor(ss, off);
        }
        if (rin == 0) {
          const int grow = ibase + rl;
          php[grow * 64 + jidx] = hp;
          phn[grow * 64 + jidx] = hn;
          pst[grow * 64 + jidx] = st;
          pss[grow * 64 + jidx] = ss;
        }
      }
    }

    if (ib != jb) {  // dir-2: mirror rows (jbase+*), chunk 2ib+wm
      const int iidx = (ib << 1) + wm;
#pragma unroll
      for (int nj = 0; nj < 4; ++nj) {
        float hp = hp2[nj], hn = hn2[nj], st = st2[nj], ss = ss2[nj];
#pragma unroll
        for (int off = 16; off < 64; off <<= 1) {
          hp = fmaxf(hp, __shfl_xor(hp, off));
          hn = fminf(hn, __shfl_xor(hn, off));
          st += __shfl_xor(st, off);
          ss += __shfl_xor(ss, off);
        }
        if (g4 == 0) {
          const int grow = jbase + (wn << 6) + (nj << 4) + rin;
          php[grow * 64 + iidx] = hp;
          phn[grow * 64 + iidx] = hn;
          pst[grow * 64 + iidx] = st;
          pss[grow * 64 + iidx] = ss;
        }
      }
    }
  }
}

// ---------------- kernel 4: combine partials, per-row margin ----------------
// 16 lanes per row, float4 loads over [row][64] partials; 16 rows per block.
__global__ __launch_bounds__(256) void k_fin1(
    const int* __restrict__ labels, const float* __restrict__ counts,
    const float* __restrict__ uncert, const float* __restrict__ cd2,
    const float* __restrict__ php, const float* __restrict__ phn,
    const float* __restrict__ pst, const float* __restrict__ pss,
    float* __restrict__ pf) {
  const int t = threadIdx.x;
  const int sub = t & 15;
  const int rw = t >> 4;
  const int row = blockIdx.x * 16 + rw;
  const int base = row * 64 + sub * 4;
  const float4 vp = *(const float4*)&php[base];
  const float4 vn = *(const float4*)&phn[base];
  const float4 vt = *(const float4*)&pst[base];
  const float4 vs = *(const float4*)&pss[base];
  float hp = fmaxf(fmaxf(vp.x, vp.y), fmaxf(vp.z, vp.w));
  float hn = fminf(fminf(vn.x, vn.y), fminf(vn.z, vn.w));
  float st = vt.x + vt.y + vt.z + vt.w;
  float ss = vs.x + vs.y + vs.z + vs.w;
#pragma unroll
  for (int off = 1; off < 16; off <<= 1) {
    hp = fmaxf(hp, __shfl_xor(hp, off));
    hn = fminf(hn, __shfl_xor(hn, off));
    st += __shfl_xor(st, off);
    ss += __shfl_xor(ss, off);
  }
  __shared__ float r1[16], r2[16];
  if (sub == 0) {
    const int lab = labels[row];
    const float cnt = counts[lab];
    const float pos = cnt - 1.f;
    const float neg = (float)NN - cnt;
    const float mean_pos = ss / fmaxf(pos, 1.f);
    const float mean_neg = (st - ss) / fmaxf(neg, 1.f);
    const float c2 = cd2[row];
    const float cdist = (c2 > 0.f) ? sqrtf(c2) : 0.f;
    const float margin = 0.1f + 0.1f * (mean_neg - mean_pos) + 0.1f * (cdist * uncert[lab]);
    const float ps = fmaxf(hp - hn + margin, 0.f);
    const bool valid = (pos > 0.f) && (neg > 0.f);
    r1[rw] = valid ? ps : 0.f;
    r2[rw] = valid ? 1.f : 0.f;
  }
  __syncthreads();
  if (t == 0) {
    float s = 0.f, c = 0.f;
#pragma unroll
    for (int k = 0; k < 16; ++k) { s += r1[k]; c += r2[k]; }
    pf[2 * blockIdx.x] = s;
    pf[2 * blockIdx.x + 1] = c;
  }
}

// ---------------- kernel 5: final scalar ----------------
__global__ __launch_bounds__(256) void k_fin2(const float* __restrict__ pf,
                                              float* __restrict__ out) {
  const int t = threadIdx.x;
  const int lane = t & 63;
  const int w = t >> 6;
  float s = pf[2 * t];
  float c = pf[2 * t + 1];
#pragma unroll
  for (int off = 1; off < 64; off <<= 1) {
    s += __shfl_xor(s, off);
    c += __shfl_xor(c, off);
  }
  __shared__ float ws1[4], ws2[4];
  if (lane == 0) { ws1[w] = s; ws2[w] = c; }
  __syncthreads();
  if (t == 0) {
    s = ws1[0] + ws1[1] + ws1[2] + ws1[3];
    c = ws2[0] + ws2[1] + ws2[2] + ws2[3];
    out[0] = (c > 0.f) ? (s / fmaxf(c, 1.f)) : 0.f;
  }
}

extern "C" void kernel_launch(void* const* d_in, const int* in_sizes, int n_in,
                              void* d_out, int out_size, void* d_ws, size_t ws_size,
                              hipStream_t stream) {
  (void)in_sizes; (void)n_in; (void)out_size; (void)ws_size;
  const float* feats = (const float*)d_in[0];
  const int* labels = (const int*)d_in[1];
  char* w = (char*)d_ws;
  float* counts = (float*)(w + 0);
  float* uncert = (float*)(w + 1024);
  float* sqb    = (float*)(w + 2048);
  float* cd2    = (float*)(w + 18432);
  float* pf     = (float*)(w + 34816);          // 512 floats
  float* cmean  = (float*)(w + 36864);
  unsigned short* fb = (unsigned short*)(w + 167936);
  float* php = (float*)(w + 4362240);           // [4096][64]
  float* phn = (float*)(w + 5410816);
  float* pst = (float*)(w + 6459392);
  float* pss = (float*)(w + 7507968);

  k_stats<<<dim3(64), dim3(512), 0, stream>>>(feats, labels, counts, cmean, uncert);
  k_row<<<dim3(1024), dim3(256), 0, stream>>>(feats, labels, cmean, fb, sqb, cd2);
  k_gemm<<<dim3(512), dim3(256), 0, stream>>>(fb, sqb, labels, php, phn, pst, pss);
  k_fin1<<<dim3(256), dim3(256), 0, stream>>>(labels, counts, uncert, cd2,
                                              php, phn, pst, pss, pf);
  k_fin2<<<dim3(1), dim3(256), 0, stream>>>(pf, (float*)d_out);
}

// Round 6
// 55.269 us; speedup vs baseline: 1.5138x; 1.3717x over previous
//
#include <hip/hip_runtime.h>
#include <hip/hip_bf16.h>

// AdaptiveTripletLoss on MI355X (gfx950).
// feats [4096,512] f32, labels [4096] i32 -> scalar f32 loss.
// R5: k_gemm moved to the m97 regime: SINGLE-buffered 34KB LDS, 2-barrier
// K-step, __launch_bounds__(256,3) (VGPR<=170 -> 3 blocks/CU; dbuf was fake
// anyway since the barrier drains vmcnt(0) including same-step prefetch).
// 528 symmetric tiles all co-resident (<=768 slots) -> no straggler rounds.

#define NN 4096
#define DD 512
#define NCLS 64

typedef __bf16 bf16x8 __attribute__((ext_vector_type(8)));
typedef float f32x4 __attribute__((ext_vector_type(4)));

__device__ __forceinline__ void gload_lds16(const void* g, void* l) {
  __builtin_amdgcn_global_load_lds(
      (const __attribute__((address_space(1))) void*)g,
      (__attribute__((address_space(3))) void*)l, 16, 0, 0);
}

// ---------------- kernel 1: per-class stats ----------------
__global__ __launch_bounds__(512) void k_stats(
    const float* __restrict__ feats, const int* __restrict__ labels,
    float* __restrict__ counts, float* __restrict__ cmean,
    float* __restrict__ uncert) {
  __shared__ __align__(16) int slab[NN];
  __shared__ int list[NN];
  __shared__ int chunk_off[64];
  __shared__ int sM;
  __shared__ float sred[512];
  const int c = blockIdx.x;
  const int t = threadIdx.x;
  const int lane = t & 63;
  const int wv = t >> 6;
  for (int i = t; i < NN; i += 512) slab[i] = labels[i];
  __syncthreads();
  for (int ch = wv; ch < 64; ch += 8) {
    const unsigned long long m = __ballot(slab[ch * 64 + lane] == c);
    if (lane == 0) chunk_off[ch] = __popcll(m);
  }
  __syncthreads();
  if (wv == 0) {
    const int v = chunk_off[lane];
    int inc = v;
#pragma unroll
    for (int off = 1; off < 64; off <<= 1) {
      const int o = __shfl_up(inc, off);
      if (lane >= off) inc += o;
    }
    chunk_off[lane] = inc - v;
    if (lane == 63) sM = inc;
  }
  __syncthreads();
  const int M = sM;
  for (int ch = wv; ch < 64; ch += 8) {
    const bool my = (slab[ch * 64 + lane] == c);
    const unsigned long long m = __ballot(my);
    if (my) {
      const int pos = chunk_off[ch] + __popcll(m & ((1ULL << lane) - 1ULL));
      list[pos] = ch * 64 + lane;
    }
  }
  __syncthreads();
  float s1 = 0.f, s2 = 0.f;
  int m = 0;
  for (; m + 8 <= M; m += 8) {
    float v[8];
#pragma unroll
    for (int e = 0; e < 8; ++e) v[e] = feats[(size_t)list[m + e] * DD + t];
#pragma unroll
    for (int e = 0; e < 8; ++e) { s1 += v[e]; s2 += v[e] * v[e]; }
  }
  for (; m < M; ++m) {
    const float v = feats[(size_t)list[m] * DD + t];
    s1 += v; s2 += v * v;
  }
  const float den = fmaxf((float)M, 1.f);
  const float mean = s1 / den;
  const float var = fmaxf(s2 / den - mean * mean, 0.f);
  cmean[c * DD + t] = mean;
  sred[t] = var;
  __syncthreads();
  for (int s = 256; s > 0; s >>= 1) {
    if (t < s) sred[t] += sred[t + s];
    __syncthreads();
  }
  if (t == 0) {
    uncert[c] = sred[0] / (float)DD;
    counts[c] = (float)M;
  }
}

// ---------------- kernel 2: per-row transform ----------------
__global__ __launch_bounds__(256) void k_row(
    const float* __restrict__ feats, const int* __restrict__ labels,
    const float* __restrict__ cmean, unsigned short* __restrict__ fb,
    float* __restrict__ sqb, float* __restrict__ cd2) {
  const int w = threadIdx.x >> 6;
  const int lane = threadIdx.x & 63;
  const int row = blockIdx.x * 4 + w;
  const int lab = labels[row];
  const float4* fr = (const float4*)(feats + (size_t)row * DD);
  const float4* cm = (const float4*)(cmean + (size_t)lab * DD);
  float sq = 0.f, c2 = 0.f;
  unsigned int ob[4];
#pragma unroll
  for (int h = 0; h < 2; ++h) {
    const float4 f = fr[lane * 2 + h];
    const float4 cv = cm[lane * 2 + h];
    const float fe[4] = {f.x, f.y, f.z, f.w};
    const float ce[4] = {cv.x, cv.y, cv.z, cv.w};
    unsigned short us[4];
#pragma unroll
    for (int e = 0; e < 4; ++e) {
      const __bf16 b = (__bf16)fe[e];
      const float bf = (float)b;
      sq += bf * bf;
      const float dd = fe[e] - ce[e];
      c2 += dd * dd;
      us[e] = __builtin_bit_cast(unsigned short, b);
    }
    ob[h * 2]     = (unsigned int)us[0] | ((unsigned int)us[1] << 16);
    ob[h * 2 + 1] = (unsigned int)us[2] | ((unsigned int)us[3] << 16);
  }
  *(uint4*)(fb + (size_t)row * DD + lane * 8) = make_uint4(ob[0], ob[1], ob[2], ob[3]);
#pragma unroll
  for (int off = 32; off > 0; off >>= 1) {
    sq += __shfl_xor(sq, off);
    c2 += __shfl_xor(c2, off);
  }
  if (lane == 0) {
    sqb[row] = sq;
    cd2[row] = c2;
  }
}

// ---------------- kernel 3: symmetric fused Gram, m97 regime ----------------
// 528 upper-triangle 128x128 tiles, one per block, all co-resident at
// 3 blocks/CU. Single 32KB LDS buffer, stage->sync->MFMA->sync per BK=64
// K-step; cross-block wave overlap hides staging latency (m97 mechanism).
__global__ __launch_bounds__(256, 3) void k_gemm(
    const unsigned short* __restrict__ fb, const float* __restrict__ sqb,
    const int* __restrict__ labels,
    float* __restrict__ php, float* __restrict__ phn,
    float* __restrict__ pst, float* __restrict__ pss) {
  __shared__ __align__(16) unsigned short sA[128 * 64];
  __shared__ __align__(16) unsigned short sB[128 * 64];
  __shared__ int s_labi[128], s_labj[128];
  __shared__ float s_sqi[128], s_sqj[128];

  const int bid = blockIdx.x;
  const int swz = (bid & 7) * 66 + (bid >> 3);  // bijective: 528 = 8*66
  int kk = swz, ib = 0;
  while (kk >= 32 - ib) { kk -= 32 - ib; ++ib; }  // triangular decode
  const int jb = ib + kk;
  const int ibase = ib << 7, jbase = jb << 7;
  const int t = threadIdx.x;
  const int lane = t & 63;
  const int w = t >> 6;
  const int wm = w >> 1, wn = w & 1;
  const int rin = lane & 15;
  const int g4 = lane >> 4;
  const int swzbyte = (g4 ^ (rin & 7)) << 4;
  const int abase = ((wm << 6) + rin) << 7;
  const int bbase = ((wn << 6) + rin) << 7;

  if (t < 128) {
    s_labi[t] = labels[ibase + t];
    s_labj[t] = labels[jbase + t];
    s_sqi[t] = sqb[ibase + t];
    s_sqj[t] = sqb[jbase + t];
  }

  f32x4 acc[4][4];
#pragma unroll
  for (int mi = 0; mi < 4; ++mi)
#pragma unroll
    for (int nj = 0; nj < 4; ++nj)
      acc[mi][nj] = (f32x4){0.f, 0.f, 0.f, 0.f};

  for (int kt = 0; kt < 8; ++kt) {
    // stage BK=64 slab (swizzled chunks: store ch^(row&7))
#pragma unroll
    for (int r = 0; r < 4; ++r) {
      const int q = (r << 8) + t;
      const int row = q >> 3;
      const int ch = q & 7;
      const int ksrc = (kt << 6) + ((ch ^ (row & 7)) << 3);
      gload_lds16(fb + (size_t)(ibase + row) * DD + ksrc, &sA[q << 3]);
      gload_lds16(fb + (size_t)(jbase + row) * DD + ksrc, &sB[q << 3]);
    }
    __syncthreads();  // loads landed in LDS
    const char* A = (const char*)sA;
    const char* B = (const char*)sB;
#pragma unroll
    for (int ks = 0; ks < 2; ++ks) {
      bf16x8 af[4], bg[4];
#pragma unroll
      for (int mi = 0; mi < 4; ++mi)
        af[mi] = *(const bf16x8*)(A + abase + (mi << 11) + (swzbyte ^ (ks << 6)));
#pragma unroll
      for (int nj = 0; nj < 4; ++nj)
        bg[nj] = *(const bf16x8*)(B + bbase + (nj << 11) + (swzbyte ^ (ks << 6)));
#pragma unroll
      for (int mi = 0; mi < 4; ++mi)
#pragma unroll
        for (int nj = 0; nj < 4; ++nj)
          acc[mi][nj] = __builtin_amdgcn_mfma_f32_16x16x32_bf16(
              af[mi], bg[nj], acc[mi][nj], 0, 0, 0);
    }
    __syncthreads();  // all waves done reading before next stage overwrites
  }

  // epilogue. C/D layout: i = wm*64+mi*16+g4*4+r, j = wn*64+nj*16+rin.
  float qj[4];
  int lj[4];
#pragma unroll
  for (int nj = 0; nj < 4; ++nj) {
    const int cl = (wn << 6) + (nj << 4) + rin;
    qj[nj] = s_sqj[cl];
    lj[nj] = s_labj[cl];
  }
  float hp2[4], hn2[4], st2[4], ss2[4];
#pragma unroll
  for (int nj = 0; nj < 4; ++nj) { hp2[nj] = 0.f; hn2[nj] = 1e30f; st2[nj] = 0.f; ss2[nj] = 0.f; }

  const int jidx = (jb << 1) + wn;
#pragma unroll
  for (int mi = 0; mi < 4; ++mi) {
#pragma unroll
    for (int r = 0; r < 4; ++r) {
      const int rl = (wm << 6) + (mi << 4) + (g4 << 2) + r;
      const float qi = s_sqi[rl];
      const int li = s_labi[rl];
      float hp = 0.f, hn = 1e30f, st = 0.f, ss = 0.f;
#pragma unroll
      for (int nj = 0; nj < 4; ++nj) {
        const float g = acc[mi][nj][r];
        float d2 = qi + qj[nj] - 2.f * g;
        d2 = fmaxf(d2, 0.f);
        const float dist = sqrtf(d2);
        const bool same = (li == lj[nj]);
        const float dp = same ? dist : 0.f;
        const float dn = same ? 1e30f : dist;
        hp = fmaxf(hp, dp);
        hn = fminf(hn, dn);
        st += dist;
        ss += dp;
        hp2[nj] = fmaxf(hp2[nj], dp);   // dir-2 (reduce over i)
        hn2[nj] = fminf(hn2[nj], dn);
        st2[nj] += dist;
        ss2[nj] += dp;
      }
#pragma unroll
      for (int off = 1; off < 16; off <<= 1) {
        hp = fmaxf(hp, __shfl_xor(hp, off));
        hn = fminf(hn, __shfl_xor(hn, off));
        st += __shfl_xor(st, off);
        ss += __shfl_xor(ss, off);
      }
      if (rin == 0) {
        const int grow = ibase + rl;
        php[grow * 64 + jidx] = hp;
        phn[grow * 64 + jidx] = hn;
        pst[grow * 64 + jidx] = st;
        pss[grow * 64 + jidx] = ss;
      }
    }
  }

  if (ib != jb) {  // dir-2: mirror rows (jbase+*), chunk 2ib+wm
    const int iidx = (ib << 1) + wm;
#pragma unroll
    for (int nj = 0; nj < 4; ++nj) {
      float hp = hp2[nj], hn = hn2[nj], st = st2[nj], ss = ss2[nj];
#pragma unroll
      for (int off = 16; off < 64; off <<= 1) {
        hp = fmaxf(hp, __shfl_xor(hp, off));
        hn = fminf(hn, __shfl_xor(hn, off));
        st += __shfl_xor(st, off);
        ss += __shfl_xor(ss, off);
      }
      if (g4 == 0) {
        const int grow = jbase + (wn << 6) + (nj << 4) + rin;
        php[grow * 64 + iidx] = hp;
        phn[grow * 64 + iidx] = hn;
        pst[grow * 64 + iidx] = st;
        pss[grow * 64 + iidx] = ss;
      }
    }
  }
}

// ---------------- kernel 4: combine partials, per-row margin ----------------
__global__ __launch_bounds__(256) void k_fin1(
    const int* __restrict__ labels, const float* __restrict__ counts,
    const float* __restrict__ uncert, const float* __restrict__ cd2,
    const float* __restrict__ php, const float* __restrict__ phn,
    const float* __restrict__ pst, const float* __restrict__ pss,
    float* __restrict__ pf) {
  const int t = threadIdx.x;
  const int sub = t & 15;
  const int rw = t >> 4;
  const int row = blockIdx.x * 16 + rw;
  const int base = row * 64 + sub * 4;
  const float4 vp = *(const float4*)&php[base];
  const float4 vn = *(const float4*)&phn[base];
  const float4 vt = *(const float4*)&pst[base];
  const float4 vs = *(const float4*)&pss[base];
  float hp = fmaxf(fmaxf(vp.x, vp.y), fmaxf(vp.z, vp.w));
  float hn = fminf(fminf(vn.x, vn.y), fminf(vn.z, vn.w));
  float st = vt.x + vt.y + vt.z + vt.w;
  float ss = vs.x + vs.y + vs.z + vs.w;
#pragma unroll
  for (int off = 1; off < 16; off <<= 1) {
    hp = fmaxf(hp, __shfl_xor(hp, off));
    hn = fminf(hn, __shfl_xor(hn, off));
    st += __shfl_xor(st, off);
    ss += __shfl_xor(ss, off);
  }
  __shared__ float r1[16], r2[16];
  if (sub == 0) {
    const int lab = labels[row];
    const float cnt = counts[lab];
    const float pos = cnt - 1.f;
    const float neg = (float)NN - cnt;
    const float mean_pos = ss / fmaxf(pos, 1.f);
    const float mean_neg = (st - ss) / fmaxf(neg, 1.f);
    const float c2 = cd2[row];
    const float cdist = (c2 > 0.f) ? sqrtf(c2) : 0.f;
    const float margin = 0.1f + 0.1f * (mean_neg - mean_pos) + 0.1f * (cdist * uncert[lab]);
    const float ps = fmaxf(hp - hn + margin, 0.f);
    const bool valid = (pos > 0.f) && (neg > 0.f);
    r1[rw] = valid ? ps : 0.f;
    r2[rw] = valid ? 1.f : 0.f;
  }
  __syncthreads();
  if (t == 0) {
    float s = 0.f, c = 0.f;
#pragma unroll
    for (int k = 0; k < 16; ++k) { s += r1[k]; c += r2[k]; }
    pf[2 * blockIdx.x] = s;
    pf[2 * blockIdx.x + 1] = c;
  }
}

// ---------------- kernel 5: final scalar ----------------
__global__ __launch_bounds__(256) void k_fin2(const float* __restrict__ pf,
                                              float* __restrict__ out) {
  const int t = threadIdx.x;
  const int lane = t & 63;
  const int w = t >> 6;
  float s = pf[2 * t];
  float c = pf[2 * t + 1];
#pragma unroll
  for (int off = 1; off < 64; off <<= 1) {
    s += __shfl_xor(s, off);
    c += __shfl_xor(c, off);
  }
  __shared__ float ws1[4], ws2[4];
  if (lane == 0) { ws1[w] = s; ws2[w] = c; }
  __syncthreads();
  if (t == 0) {
    s = ws1[0] + ws1[1] + ws1[2] + ws1[3];
    c = ws2[0] + ws2[1] + ws2[2] + ws2[3];
    out[0] = (c > 0.f) ? (s / fmaxf(c, 1.f)) : 0.f;
  }
}

extern "C" void kernel_launch(void* const* d_in, const int* in_sizes, int n_in,
                              void* d_out, int out_size, void* d_ws, size_t ws_size,
                              hipStream_t stream) {
  (void)in_sizes; (void)n_in; (void)out_size; (void)ws_size;
  const float* feats = (const float*)d_in[0];
  const int* labels = (const int*)d_in[1];
  char* w = (char*)d_ws;
  float* counts = (float*)(w + 0);
  float* uncert = (float*)(w + 1024);
  float* sqb    = (float*)(w + 2048);
  float* cd2    = (float*)(w + 18432);
  float* pf     = (float*)(w + 34816);          // 512 floats
  float* cmean  = (float*)(w + 36864);
  unsigned short* fb = (unsigned short*)(w + 167936);
  float* php = (float*)(w + 4362240);           // [4096][64]
  float* phn = (float*)(w + 5410816);
  float* pst = (float*)(w + 6459392);
  float* pss = (float*)(w + 7507968);

  k_stats<<<dim3(64), dim3(512), 0, stream>>>(feats, labels, counts, cmean, uncert);
  k_row<<<dim3(1024), dim3(256), 0, stream>>>(feats, labels, cmean, fb, sqb, cd2);
  k_gemm<<<dim3(528), dim3(256), 0, stream>>>(fb, sqb, labels, php, phn, pst, pss);
  k_fin1<<<dim3(256), dim3(256), 0, stream>>>(labels, counts, uncert, cd2,
                                              php, phn, pst, pss, pf);
  k_fin2<<<dim3(1), dim3(256), 0, stream>>>(pf, (float*)d_out);
}